// Round 1
// baseline (12790.960 us; speedup 1.0000x reference)
//
#include <hip/hip_runtime.h>
#include <cmath>

#define S_LEN 128
#define BATCH 32
#define HID   512
#define VOCAB 10000
#define MROWS (S_LEN * BATCH)   // 4096

// ---------------------------------------------------------------------------
// Tiled fp32 GEMM: C[M,N] = A[M,K] * B + bias[N]
//   GATHER_A: A row m comes from emb[tok[m], :]
//   B_KN:     B stored gate-blocked [g][K][512]  (Wx layout, n = g*512+col)
//   else:     B stored [N][K] row-major K-contiguous (Wy layout)
// Tile 64x64, K-tile 32, 256 threads, 4x4 microtile.
// ---------------------------------------------------------------------------
template<bool GATHER_A, bool B_KN>
__global__ __launch_bounds__(256) void gemm_kernel(
    const float* __restrict__ A, const int* __restrict__ tok,
    const float* __restrict__ Bmat, const float* __restrict__ bias,
    float* __restrict__ C, int M, int N, int K)
{
    __shared__ float As[32][68];
    __shared__ float Bs[32][68];
    __shared__ int   toks[64];

    const int tid = threadIdx.x;
    const int m0  = blockIdx.y * 64;
    const int n0  = blockIdx.x * 64;

    if (GATHER_A && tid < 64) toks[tid] = tok[m0 + tid];
    __syncthreads();

    const int tx = tid & 15;        // n-microtile
    const int ty = tid >> 4;        // m-microtile
    const int lr = tid >> 3;        // 0..31 loader row
    const int lc = (tid & 7) * 4;   // loader col (k), 0..28

    float acc[4][4] = {};

    for (int k0 = 0; k0 < K; k0 += 32) {
        // ---- load A tile (transpose to As[k][m]) ----
        #pragma unroll
        for (int rep = 0; rep < 2; rep++) {
            int r = lr + rep * 32;
            const float* arow;
            if (GATHER_A) arow = A + (size_t)toks[r] * K;
            else          arow = A + (size_t)(m0 + r) * K;
            float4 v = *(const float4*)(arow + k0 + lc);
            As[lc + 0][r] = v.x; As[lc + 1][r] = v.y;
            As[lc + 2][r] = v.z; As[lc + 3][r] = v.w;
        }
        // ---- load B tile ----
        if (B_KN) {
            int g    = n0 >> 9;
            int col0 = n0 & 511;
            const float* bbase = Bmat + (size_t)g * K * 512 + col0;
            int bc = (tid & 15) * 4;   // n-local float4
            int bk = tid >> 4;         // 0..15
            #pragma unroll
            for (int rep = 0; rep < 2; rep++) {
                int kk = bk + rep * 16;
                float4 v = *(const float4*)(bbase + (size_t)(k0 + kk) * 512 + bc);
                *(float4*)&Bs[kk][bc] = v;
            }
        } else {
            #pragma unroll
            for (int rep = 0; rep < 2; rep++) {
                int r = lr + rep * 32;
                int n = n0 + r;
                float4 v = make_float4(0.f, 0.f, 0.f, 0.f);
                if (n < N) v = *(const float4*)(Bmat + (size_t)n * K + k0 + lc);
                Bs[lc + 0][r] = v.x; Bs[lc + 1][r] = v.y;
                Bs[lc + 2][r] = v.z; Bs[lc + 3][r] = v.w;
            }
        }
        __syncthreads();
        // ---- compute ----
        #pragma unroll
        for (int k = 0; k < 32; k++) {
            float4 a4 = *(const float4*)&As[k][ty * 4];
            float4 b4 = *(const float4*)&Bs[k][tx * 4];
            float av[4] = {a4.x, a4.y, a4.z, a4.w};
            float bv[4] = {b4.x, b4.y, b4.z, b4.w};
            #pragma unroll
            for (int i = 0; i < 4; i++)
                #pragma unroll
                for (int j = 0; j < 4; j++)
                    acc[i][j] = fmaf(av[i], bv[j], acc[i][j]);
        }
        __syncthreads();
    }
    // ---- epilogue ----
    #pragma unroll
    for (int i = 0; i < 4; i++) {
        int m = m0 + ty * 4 + i;
        #pragma unroll
        for (int j = 0; j < 4; j++) {
            int n = n0 + tx * 4 + j;
            if (n < N) C[(size_t)m * N + n] = acc[i][j] + bias[n];
        }
    }
}

// ---------------------------------------------------------------------------
// Stage A: r,z pre-act + sigmoid for one layer.
//   rz[b, g*512+col] = sigmoid( ax[b*ax_stride + g*512+col] + sum_i h[b,i]*U[g][i][col] )
// grid: 32 b * 4 chunks = 128 blocks, 256 threads
// ---------------------------------------------------------------------------
__global__ __launch_bounds__(256) void rz_kernel(
    const float* __restrict__ h, const float* __restrict__ ax, int ax_stride,
    const float* __restrict__ U, float* __restrict__ rz)
{
    __shared__ float hs[HID];
    const int b = blockIdx.x >> 2;
    const int o = ((blockIdx.x & 3) << 8) + threadIdx.x;  // 0..1023
    const int g = o >> 9, col = o & 511;

    hs[threadIdx.x]       = h[b * HID + threadIdx.x];
    hs[threadIdx.x + 256] = h[b * HID + 256 + threadIdx.x];
    __syncthreads();

    const float* Up = U + (size_t)g * HID * HID + col;
    float acc = 0.f;
    #pragma unroll 16
    for (int i = 0; i < HID; i++) acc = fmaf(hs[i], Up[(size_t)i * HID], acc);

    float pre = ax[b * ax_stride + g * HID + col] + acc;
    rz[b * 1024 + o] = 1.f / (1.f + __expf(-pre));
}

// ---------------------------------------------------------------------------
// Stage B/D: h_hat + blend.
//   v = r*h ; pre = axh + v@U2 ; h' = (1-z)*h + z*tanh(pre)
// grid: 32 b * 2 chunks = 64 blocks, 256 threads
// ---------------------------------------------------------------------------
__global__ __launch_bounds__(256) void hprime_kernel(
    const float* __restrict__ h, const float* __restrict__ axh, int axh_stride,
    const float* __restrict__ U2, const float* __restrict__ rz,
    float* __restrict__ h_out, float* __restrict__ top)
{
    __shared__ float vs[HID];
    const int b = blockIdx.x >> 1;
    const int o = ((blockIdx.x & 1) << 8) + threadIdx.x;  // 0..511

    vs[threadIdx.x]       = rz[b * 1024 + threadIdx.x]       * h[b * HID + threadIdx.x];
    vs[threadIdx.x + 256] = rz[b * 1024 + threadIdx.x + 256] * h[b * HID + threadIdx.x + 256];
    __syncthreads();

    const float* Up = U2 + o;
    float acc = 0.f;
    #pragma unroll 16
    for (int i = 0; i < HID; i++) acc = fmaf(vs[i], Up[(size_t)i * HID], acc);

    float pre = axh[b * axh_stride + o] + acc;
    float e2  = __expf(2.f * pre);
    float hh  = 1.f - 2.f / (e2 + 1.f);          // tanh(pre), safe at +/-inf
    float z   = rz[b * 1024 + 512 + o];
    float hn  = (1.f - z) * h[b * HID + o] + z * hh;
    h_out[b * HID + o] = hn;
    if (top) top[b * HID + o] = hn;
}

// ---------------------------------------------------------------------------
// Stage C: layer-1 gates: ax1 = x@Wx1 + bx1 (all 3 gates); r,z activated with
// +h@U1[0,1]; gate-2 x-part stored raw to axh.
// grid: 32 b * 6 chunks = 192 blocks, 256 threads
// ---------------------------------------------------------------------------
__global__ __launch_bounds__(256) void l1_gate_kernel(
    const float* __restrict__ x, const float* __restrict__ h,
    const float* __restrict__ Wx1, const float* __restrict__ bx1,
    const float* __restrict__ U1,
    float* __restrict__ rz, float* __restrict__ axh)
{
    __shared__ float xs[HID];
    __shared__ float hs[HID];
    const int b = blockIdx.x / 6;
    const int o = (blockIdx.x % 6) * 256 + threadIdx.x;  // 0..1535
    const int g = o >> 9, col = o & 511;

    xs[threadIdx.x]       = x[b * HID + threadIdx.x];
    xs[threadIdx.x + 256] = x[b * HID + 256 + threadIdx.x];
    hs[threadIdx.x]       = h[b * HID + threadIdx.x];
    hs[threadIdx.x + 256] = h[b * HID + 256 + threadIdx.x];
    __syncthreads();

    const float* Wp = Wx1 + (size_t)g * HID * HID + col;
    float acc = bx1[g * HID + col];
    #pragma unroll 8
    for (int i = 0; i < HID; i++) acc = fmaf(xs[i], Wp[(size_t)i * HID], acc);

    if (g < 2) {
        const float* Up = U1 + (size_t)g * HID * HID + col;
        float acc2 = 0.f;
        #pragma unroll 8
        for (int i = 0; i < HID; i++) acc2 = fmaf(hs[i], Up[(size_t)i * HID], acc2);
        rz[b * 1024 + g * HID + col] = 1.f / (1.f + __expf(-(acc + acc2)));
    } else {
        axh[b * HID + col] = acc;
    }
}

__global__ __launch_bounds__(256) void copy_kernel(
    const float* __restrict__ src, float* __restrict__ dst, int n)
{
    int i = blockIdx.x * 256 + threadIdx.x;
    if (i < n) dst[i] = src[i];
}

// ---------------------------------------------------------------------------
extern "C" void kernel_launch(void* const* d_in, const int* in_sizes, int n_in,
                              void* d_out, int out_size, void* d_ws, size_t ws_size,
                              hipStream_t stream)
{
    const int*   tokens = (const int*)  d_in[0];   // [S,B]
    const float* h0     = (const float*)d_in[1];   // [L,B,H] (zeros)
    const float* emb    = (const float*)d_in[2];   // [V,H]
    const float* Wx     = (const float*)d_in[3];   // [L,3,H,H]
    const float* bx     = (const float*)d_in[4];   // [L,3,H]
    const float* U      = (const float*)d_in[5];   // [L,3,H,H]
    const float* Wy     = (const float*)d_in[6];   // [V,H]
    const float* by     = (const float*)d_in[7];   // [V]
    float*       out    = (float*)d_out;

    // workspace layout (floats)
    float* ws   = (float*)d_ws;
    float* ax0  = ws;                              // MROWS*1536
    float* tops = ax0  + (size_t)MROWS * 1536;     // MROWS*512
    float* h0b  = tops + (size_t)MROWS * 512;      // 2 * B*H
    float* h1b  = h0b  + 2 * BATCH * HID;          // 2 * B*H
    float* rz0  = h1b  + 2 * BATCH * HID;          // B*1024
    float* rz1  = rz0  + BATCH * 1024;             // B*1024
    float* axh1 = rz1  + BATCH * 1024;             // B*512

    const int HH = HID * HID;

    // init hidden state from h0 input
    copy_kernel<<<64, 256, 0, stream>>>(h0,                 h0b, BATCH * HID);
    copy_kernel<<<64, 256, 0, stream>>>(h0 + BATCH * HID,   h1b, BATCH * HID);

    // ax0 = emb[tokens] @ Wx[0] + bx[0]   (M=4096, N=1536, K=512)
    gemm_kernel<true, true><<<dim3(1536 / 64, MROWS / 64), 256, 0, stream>>>(
        emb, tokens, Wx, bx, ax0, MROWS, 1536, HID);

    // sequential scan
    for (int t = 0; t < S_LEN; t++) {
        float* h0_in  = h0b + (t & 1) * BATCH * HID;
        float* h0_out = h0b + ((t + 1) & 1) * BATCH * HID;
        float* h1_in  = h1b + (t & 1) * BATCH * HID;
        float* h1_out = h1b + ((t + 1) & 1) * BATCH * HID;
        const float* ax0_t = ax0 + (size_t)t * BATCH * 1536;

        // layer 0: r,z
        rz_kernel<<<128, 256, 0, stream>>>(h0_in, ax0_t, 1536, U, rz0);
        // layer 0: h'
        hprime_kernel<<<64, 256, 0, stream>>>(h0_in, ax0_t + 1024, 1536,
                                              U + 2 * HH, rz0, h0_out, nullptr);
        // layer 1: gates (ax1 + r,z)
        l1_gate_kernel<<<192, 256, 0, stream>>>(h0_out, h1_in,
                                                Wx + 3 * HH, bx + 1536,
                                                U + 3 * HH, rz1, axh1);
        // layer 1: h' (also writes tops[t])
        hprime_kernel<<<64, 256, 0, stream>>>(h1_in, axh1, 512,
                                              U + 3 * HH + 2 * HH, rz1, h1_out,
                                              tops + (size_t)t * BATCH * HID);
    }

    // h_final -> out tail (after 128 steps, current state is in buffer 0)
    const size_t logits_sz = (size_t)MROWS * VOCAB;   // 40,960,000
    copy_kernel<<<64, 256, 0, stream>>>(h0b, out + logits_sz,              BATCH * HID);
    copy_kernel<<<64, 256, 0, stream>>>(h1b, out + logits_sz + BATCH * HID, BATCH * HID);

    // logits = tops @ Wy^T + by   (M=4096, N=10000, K=512)
    gemm_kernel<false, false><<<dim3((VOCAB + 63) / 64, MROWS / 64), 256, 0, stream>>>(
        tops, nullptr, Wy, by, out, MROWS, VOCAB, HID);
}

// Round 2
// 6676.476 us; speedup vs baseline: 1.9158x; 1.9158x over previous
//
#include <hip/hip_runtime.h>
#include <cmath>

#define S_LEN 128
#define BATCH 32
#define HID   512
#define VOCAB 10000
#define MROWS (S_LEN * BATCH)   // 4096
#define HH    (HID * HID)

// ---------------------------------------------------------------------------
// Tiled fp32 GEMM: C[M,N] = A[M,K] * B + bias[N]
//   GATHER_A: A row m comes from emb[tok[m], :]
//   B_KN:     B stored gate-blocked [g][K][512]  (Wx layout, n = g*512+col)
//   else:     B stored [N][K] row-major K-contiguous (Wy layout)
// Tile 64x64, K-tile 32, 256 threads, 4x4 microtile.
// ---------------------------------------------------------------------------
template<bool GATHER_A, bool B_KN>
__global__ __launch_bounds__(256) void gemm_kernel(
    const float* __restrict__ A, const int* __restrict__ tok,
    const float* __restrict__ Bmat, const float* __restrict__ bias,
    float* __restrict__ C, int M, int N, int K)
{
    __shared__ float As[32][68];
    __shared__ float Bs[32][68];
    __shared__ int   toks[64];

    const int tid = threadIdx.x;
    const int m0  = blockIdx.y * 64;
    const int n0  = blockIdx.x * 64;

    if (GATHER_A && tid < 64) toks[tid] = tok[m0 + tid];
    __syncthreads();

    const int tx = tid & 15;        // n-microtile
    const int ty = tid >> 4;        // m-microtile
    const int lr = tid >> 3;        // 0..31 loader row
    const int lc = (tid & 7) * 4;   // loader col (k), 0..28

    float acc[4][4] = {};

    for (int k0 = 0; k0 < K; k0 += 32) {
        #pragma unroll
        for (int rep = 0; rep < 2; rep++) {
            int r = lr + rep * 32;
            const float* arow;
            if (GATHER_A) arow = A + (size_t)toks[r] * K;
            else          arow = A + (size_t)(m0 + r) * K;
            float4 v = *(const float4*)(arow + k0 + lc);
            As[lc + 0][r] = v.x; As[lc + 1][r] = v.y;
            As[lc + 2][r] = v.z; As[lc + 3][r] = v.w;
        }
        if (B_KN) {
            int g    = n0 >> 9;
            int col0 = n0 & 511;
            const float* bbase = Bmat + (size_t)g * K * 512 + col0;
            int bc = (tid & 15) * 4;
            int bk = tid >> 4;
            #pragma unroll
            for (int rep = 0; rep < 2; rep++) {
                int kk = bk + rep * 16;
                float4 v = *(const float4*)(bbase + (size_t)(k0 + kk) * 512 + bc);
                *(float4*)&Bs[kk][bc] = v;
            }
        } else {
            #pragma unroll
            for (int rep = 0; rep < 2; rep++) {
                int r = lr + rep * 32;
                int n = n0 + r;
                float4 v = make_float4(0.f, 0.f, 0.f, 0.f);
                if (n < N) v = *(const float4*)(Bmat + (size_t)n * K + k0 + lc);
                Bs[lc + 0][r] = v.x; Bs[lc + 1][r] = v.y;
                Bs[lc + 2][r] = v.z; Bs[lc + 3][r] = v.w;
            }
        }
        __syncthreads();
        #pragma unroll
        for (int k = 0; k < 32; k++) {
            float4 a4 = *(const float4*)&As[k][ty * 4];
            float4 b4 = *(const float4*)&Bs[k][tx * 4];
            float av[4] = {a4.x, a4.y, a4.z, a4.w};
            float bv[4] = {b4.x, b4.y, b4.z, b4.w};
            #pragma unroll
            for (int i = 0; i < 4; i++)
                #pragma unroll
                for (int j = 0; j < 4; j++)
                    acc[i][j] = fmaf(av[i], bv[j], acc[i][j]);
        }
        __syncthreads();
    }
    #pragma unroll
    for (int i = 0; i < 4; i++) {
        int m = m0 + ty * 4 + i;
        #pragma unroll
        for (int j = 0; j < 4; j++) {
            int n = n0 + tx * 4 + j;
            if (n < N) C[(size_t)m * N + n] = acc[i][j] + bias[n];
        }
    }
}

// ---------------------------------------------------------------------------
// Persistent per-batch-element GRU layer scan. One block per b (32 blocks,
// 1024 threads). Runs all S_LEN steps for ONE layer with only __syncthreads.
//   ax:   [S*B, 1536] precomputed x-projection (+bias), rows m = t*32+b
//   Ul:   [3, 512, 512] recurrent weights, row-major [g][k][col]
//   hseq: [S*B, 512] per-step outputs (rows m = t*32+b)
//   h0g:  [B, 512] initial hidden;  hfin: [B, 512] final hidden
//
// Per step: stage R (r,z: 1024 dot-512s, 4-way k-split, float4 cols)
//           stage H (h_hat: 512 dot-512s, 8-way k-split, float4 cols)
// ---------------------------------------------------------------------------
__global__ __launch_bounds__(1024) void scan_layer_kernel(
    const float* __restrict__ ax, const float* __restrict__ Ul,
    const float* __restrict__ h0g,
    float* __restrict__ hseq, float* __restrict__ hfin)
{
    __shared__ float hs[HID];      // current hidden state
    __shared__ float rz[1024];     // r (0..511), z (512..1023)
    __shared__ float vs[HID];      // r*h
    __shared__ float part[4096];   // k-split partial sums (16 KB)

    const int tid = threadIdx.x;
    const int b   = blockIdx.x;

    // load initial h
    if (tid < HID) hs[tid] = h0g[b * HID + tid];

    // stage-R thread mapping: 256 col-quads x 4 k-slices (128 k each)
    const int r_c4 = tid & 255;           // col quad 0..255 (col = 4*c4)
    const int r_ks = tid >> 8;            // k-slice 0..3
    const int r_g  = r_c4 >> 7;           // gate 0 (r) or 1 (z)
    const int r_wc = (r_c4 & 127) * 4;    // col within gate
    const float* Wr = Ul + (size_t)r_g * HH + (size_t)(r_ks * 128) * HID + r_wc;

    // stage-H thread mapping: 128 col-quads x 8 k-slices (64 k each)
    const int h_c4 = tid & 127;
    const int h_ks = tid >> 7;
    const float* Wh = Ul + (size_t)2 * HH + (size_t)(h_ks * 64) * HID + h_c4 * 4;

    for (int t = 0; t < S_LEN; t++) {
        const float* axrow = ax + (size_t)(t * BATCH + b) * 1536;
        __syncthreads();   // h ready

        // ---- stage R partials ----
        {
            float4 acc = make_float4(0.f, 0.f, 0.f, 0.f);
            const float* w = Wr;
            const float* hk = &hs[r_ks * 128];
            #pragma unroll 8
            for (int k = 0; k < 128; k++) {
                float h_k = hk[k];
                float4 wv = *(const float4*)(w);
                w += HID;
                acc.x = fmaf(h_k, wv.x, acc.x);
                acc.y = fmaf(h_k, wv.y, acc.y);
                acc.z = fmaf(h_k, wv.z, acc.z);
                acc.w = fmaf(h_k, wv.w, acc.w);
            }
            *(float4*)&part[r_ks * 1024 + r_c4 * 4] = acc;
        }
        __syncthreads();

        // ---- stage R reduce + sigmoid (+ v = r*h) ----
        {
            float s = part[tid] + part[1024 + tid] + part[2048 + tid] + part[3072 + tid];
            float pre = axrow[tid] + s;
            float sig = 1.f / (1.f + __expf(-pre));
            rz[tid] = sig;
            if (tid < HID) vs[tid] = sig * hs[tid];
        }
        __syncthreads();

        // ---- stage H partials ----
        {
            float4 acc = make_float4(0.f, 0.f, 0.f, 0.f);
            const float* w = Wh;
            const float* vk = &vs[h_ks * 64];
            #pragma unroll 8
            for (int k = 0; k < 64; k++) {
                float v_k = vk[k];
                float4 wv = *(const float4*)(w);
                w += HID;
                acc.x = fmaf(v_k, wv.x, acc.x);
                acc.y = fmaf(v_k, wv.y, acc.y);
                acc.z = fmaf(v_k, wv.z, acc.z);
                acc.w = fmaf(v_k, wv.w, acc.w);
            }
            *(float4*)&part[h_ks * 512 + h_c4 * 4] = acc;
        }
        __syncthreads();

        // ---- stage H reduce + tanh + blend ----
        if (tid < HID) {
            float s = 0.f;
            #pragma unroll
            for (int ks = 0; ks < 8; ks++) s += part[ks * 512 + tid];
            float pre = axrow[1024 + tid] + s;
            float e2  = __expf(2.f * pre);
            float hh  = 1.f - 2.f / (e2 + 1.f);      // tanh
            float z   = rz[512 + tid];
            float hn  = (1.f - z) * hs[tid] + z * hh;
            hs[tid] = hn;                             // same-thread read/write of hs[tid]
            hseq[(size_t)(t * BATCH + b) * HID + tid] = hn;
        }
    }
    __syncthreads();
    if (tid < HID) hfin[b * HID + tid] = hs[tid];
}

// ---------------------------------------------------------------------------
extern "C" void kernel_launch(void* const* d_in, const int* in_sizes, int n_in,
                              void* d_out, int out_size, void* d_ws, size_t ws_size,
                              hipStream_t stream)
{
    const int*   tokens = (const int*)  d_in[0];   // [S,B]
    const float* h0     = (const float*)d_in[1];   // [L,B,H]
    const float* emb    = (const float*)d_in[2];   // [V,H]
    const float* Wx     = (const float*)d_in[3];   // [L,3,H,H]
    const float* bx     = (const float*)d_in[4];   // [L,3,H]
    const float* U      = (const float*)d_in[5];   // [L,3,H,H]
    const float* Wy     = (const float*)d_in[6];   // [V,H]
    const float* by     = (const float*)d_in[7];   // [V]
    float*       out    = (float*)d_out;

    // workspace: axbuf [4096*1536] reused for ax0 then ax1; hseq [4096*512]
    // (hseq holds layer-0 outputs, then is overwritten by layer-1 outputs=tops)
    float* ws    = (float*)d_ws;
    float* axbuf = ws;                                // 6,291,456 floats
    float* hseq  = axbuf + (size_t)MROWS * 1536;      // 2,097,152 floats

    const size_t logits_sz = (size_t)MROWS * VOCAB;
    float* hfin0 = out + logits_sz;                   // [B,H]
    float* hfin1 = out + logits_sz + BATCH * HID;     // [B,H]

    // ax0 = emb[tokens] @ Wx[0] + bx[0]   (M=4096, N=1536, K=512)
    gemm_kernel<true, true><<<dim3(1536 / 64, MROWS / 64), 256, 0, stream>>>(
        emb, tokens, Wx, bx, axbuf, MROWS, 1536, HID);

    // layer-0 scan (writes hseq = layer-0 outputs for all t, final h -> out tail)
    scan_layer_kernel<<<BATCH, 1024, 0, stream>>>(
        axbuf, U, h0, hseq, hfin0);

    // ax1 = hseq @ Wx[1] + bx[1]   (M=4096, N=1536, K=512)
    gemm_kernel<false, true><<<dim3(1536 / 64, MROWS / 64), 256, 0, stream>>>(
        hseq, nullptr, Wx + 3 * HH, bx + 1536, axbuf, MROWS, 1536, HID);

    // layer-1 scan (overwrites hseq with tops, final h -> out tail)
    scan_layer_kernel<<<BATCH, 1024, 0, stream>>>(
        axbuf, U + 3 * HH, h0 + BATCH * HID, hseq, hfin1);

    // logits = tops @ Wy^T + by   (M=4096, N=10000, K=512)
    gemm_kernel<false, false><<<dim3((VOCAB + 63) / 64, MROWS / 64), 256, 0, stream>>>(
        hseq, nullptr, Wy, by, out, MROWS, VOCAB, HID);
}